// Round 1
// baseline (1454.063 us; speedup 1.0000x reference)
//
#include <hip/hip_runtime.h>

#define CH 128          // IN_CH == OUT_CH == 128
#define TM 128          // rows per GEMM block

// ---------------- degree / norm ----------------

__global__ __launch_bounds__(256) void k_init_deg(float* __restrict__ deg, int n) {
    int i = blockIdx.x * 256 + threadIdx.x;
    if (i < n) deg[i] = 1.0f;   // self-loop contributes 1 to every node's degree
}

__global__ __launch_bounds__(256) void k_count_deg(const int* __restrict__ dst,
                                                   float* __restrict__ deg, int e) {
    int i = blockIdx.x * 256 + threadIdx.x;
    if (i < e) atomicAdd(&deg[dst[i]], 1.0f);
}

__global__ __launch_bounds__(256) void k_dinv(float* __restrict__ deg, int n) {
    int i = blockIdx.x * 256 + threadIdx.x;
    if (i < n) deg[i] = rsqrtf(deg[i]);   // deg >= 1 always (self-loop), no zero check needed
}

// ---------------- GEMM: h = x @ W  (fp32, LDS tiled) ----------------
// Block: 256 threads, tile 128 rows x 128 cols.
// thread: cg = tid&7 owns cols {cg*4 + 32j, j=0..3} (conflict-free LDS banks),
//         rg = tid>>3 owns rows rbase..rbase+3.

__device__ inline void fma4(float4& a, float s, const float4& w) {
    a.x = fmaf(s, w.x, a.x); a.y = fmaf(s, w.y, a.y);
    a.z = fmaf(s, w.z, a.z); a.w = fmaf(s, w.w, a.w);
}

__global__ __launch_bounds__(256) void k_gemm(const float* __restrict__ x,
                                              const float* __restrict__ W,
                                              float* __restrict__ h, int n) {
    __shared__ float sW[CH * CH];        // 64 KiB, row-major [k][c]
    __shared__ float sX[TM * 129];       // 64.5 KiB, pad 129 (129%8==1 -> conflict-free)

    const int tid = threadIdx.x;
    const int r0  = blockIdx.x * TM;

    // stage W (16384 floats = 4096 float4, 16 per thread)
    const float4* W4 = (const float4*)W;
    float4* sW4 = (float4*)sW;
#pragma unroll
    for (int i = 0; i < 16; ++i) sW4[tid + i * 256] = W4[tid + i * 256];

    // stage x tile (128x128), scalar-store into padded rows
#pragma unroll
    for (int i = 0; i < 16; ++i) {
        int f = tid + i * 256;           // float4 index within tile
        int r = f >> 5, cq = f & 31;
        float4 v = make_float4(0.f, 0.f, 0.f, 0.f);
        if (r0 + r < n) v = ((const float4*)x)[(size_t)(r0 + r) * 32 + cq];
        float* d = &sX[r * 129 + cq * 4];
        d[0] = v.x; d[1] = v.y; d[2] = v.z; d[3] = v.w;
    }
    __syncthreads();

    const int cg = tid & 7;
    const int rbase = (tid >> 3) * 4;

    float4 acc[4][4];
#pragma unroll
    for (int i = 0; i < 4; ++i)
#pragma unroll
        for (int j = 0; j < 4; ++j) acc[i][j] = make_float4(0.f, 0.f, 0.f, 0.f);

#pragma unroll 4
    for (int k = 0; k < CH; ++k) {
        const float* wr = &sW[k * CH + cg * 4];
        float4 w0 = *(const float4*)(wr);
        float4 w1 = *(const float4*)(wr + 32);
        float4 w2 = *(const float4*)(wr + 64);
        float4 w3 = *(const float4*)(wr + 96);
#pragma unroll
        for (int i = 0; i < 4; ++i) {
            float xv = sX[(rbase + i) * 129 + k];
            fma4(acc[i][0], xv, w0);
            fma4(acc[i][1], xv, w1);
            fma4(acc[i][2], xv, w2);
            fma4(acc[i][3], xv, w3);
        }
    }

#pragma unroll
    for (int i = 0; i < 4; ++i) {
        int row = r0 + rbase + i;
        if (row < n) {
            float4* hr = (float4*)(h + (size_t)row * CH);
            hr[cg]      = acc[i][0];
            hr[cg + 8]  = acc[i][1];
            hr[cg + 16] = acc[i][2];
            hr[cg + 24] = acc[i][3];
        }
    }
}

// ---------------- scatter: out[dst] += norm * h[src] (atomics) ----------------
// 32 lanes per edge, one float4 per lane.

__global__ __launch_bounds__(256) void k_scatter(const float4* __restrict__ h4,
                                                 const int* __restrict__ ei,
                                                 const float* __restrict__ dinv,
                                                 float* __restrict__ out, int e) {
    int idx  = blockIdx.x * 256 + threadIdx.x;
    int edge = idx >> 5, lane = idx & 31;
    if (edge >= e) return;
    int s = ei[edge];
    int d = ei[e + edge];
    float nrm = dinv[s] * dinv[d];
    float4 v = h4[(size_t)s * 32 + lane];
    float* op = out + (size_t)d * CH + lane * 4;
    atomicAdd(op + 0, v.x * nrm);
    atomicAdd(op + 1, v.y * nrm);
    atomicAdd(op + 2, v.z * nrm);
    atomicAdd(op + 3, v.w * nrm);
}

// ---------------- epilogue: out = relu(out + h*dinv^2 + b) (self-loop fused) ----

__global__ __launch_bounds__(256) void k_finish(float4* __restrict__ out4,
                                                const float4* __restrict__ h4,
                                                const float* __restrict__ dinv,
                                                const float4* __restrict__ b4,
                                                int n) {
    int idx = blockIdx.x * 256 + threadIdx.x;
    if (idx >= n * 32) return;
    int node = idx >> 5, q = idx & 31;
    float di = dinv[node];
    float sc = di * di;
    float4 v = out4[idx];
    float4 hh = h4[idx];
    float4 bb = b4[q];
    v.x = fmaxf(fmaf(hh.x, sc, v.x) + bb.x, 0.f);
    v.y = fmaxf(fmaf(hh.y, sc, v.y) + bb.y, 0.f);
    v.z = fmaxf(fmaf(hh.z, sc, v.z) + bb.z, 0.f);
    v.w = fmaxf(fmaf(hh.w, sc, v.w) + bb.w, 0.f);
    out4[idx] = v;
}

// ---------------- launch ----------------

extern "C" void kernel_launch(void* const* d_in, const int* in_sizes, int n_in,
                              void* d_out, int out_size, void* d_ws, size_t ws_size,
                              hipStream_t stream) {
    const float* x  = (const float*)d_in[0];
    const int*   ei = (const int*)d_in[1];
    const float* W  = (const float*)d_in[2];
    const float* b  = (const float*)d_in[3];
    float* out = (float*)d_out;

    const int N = in_sizes[0] / CH;     // 50000
    const int E = in_sizes[1] / 2;      // 800000

    // ws layout: [0, 200000) deg/dinv; [262144, +25.6MB) h
    float* deg = (float*)d_ws;
    float* h   = (float*)((char*)d_ws + 262144);

    hipMemsetAsync(d_out, 0, (size_t)out_size * sizeof(float), stream);

    k_init_deg<<<(N + 255) / 256, 256, 0, stream>>>(deg, N);
    k_count_deg<<<(E + 255) / 256, 256, 0, stream>>>(ei + E, deg, E);
    k_dinv<<<(N + 255) / 256, 256, 0, stream>>>(deg, N);

    k_gemm<<<(N + TM - 1) / TM, 256, 0, stream>>>(x, W, h, N);

    int sthreads = E * 32;
    k_scatter<<<(sthreads + 255) / 256, 256, 0, stream>>>((const float4*)h, ei, deg, out, E);

    k_finish<<<((N * 32) + 255) / 256, 256, 0, stream>>>((float4*)out, (const float4*)h,
                                                         deg, (const float4*)b, N);
}

// Round 2
// 242.938 us; speedup vs baseline: 5.9853x; 5.9853x over previous
//
#include <hip/hip_runtime.h>

#define CH 128          // IN_CH == OUT_CH == 128
#define TM 128          // rows per GEMM block

static __host__ __device__ inline size_t align256(size_t x) { return (x + 255) & ~(size_t)255; }

// ---------------- degree histogram / norm ----------------

__global__ __launch_bounds__(256) void k_hist(const int* __restrict__ dst,
                                              int* __restrict__ cnt, int e) {
    int i = blockIdx.x * 256 + threadIdx.x;
    if (i < e) atomicAdd(&cnt[dst[i]], 1);
}

__global__ __launch_bounds__(256) void k_dinv(const int* __restrict__ cnt,
                                              float* __restrict__ dinv, int n) {
    int i = blockIdx.x * 256 + threadIdx.x;
    if (i < n) dinv[i] = rsqrtf((float)cnt[i] + 1.0f);   // +1 self-loop
}

// ---------------- exclusive scan of counts -> rowptr (single block) ----------------

__global__ __launch_bounds__(1024) void k_scan(const int* __restrict__ cnt,
                                               int* __restrict__ rowptr, int n) {
    __shared__ int wsum[16];
    __shared__ int carry;
    const int tid = threadIdx.x;
    const int lane = tid & 63, wid = tid >> 6;
    if (tid == 0) { carry = 0; rowptr[0] = 0; }
    __syncthreads();
    for (int base = 0; base < n; base += 1024) {
        int i = base + tid;
        int v = (i < n) ? cnt[i] : 0;
        // inclusive wave scan (64 lanes)
        int s = v;
#pragma unroll
        for (int off = 1; off < 64; off <<= 1) {
            int t = __shfl_up(s, off, 64);
            if (lane >= off) s += t;
        }
        if (lane == 63) wsum[wid] = s;
        __syncthreads();
        if (wid == 0) {
            int ws = (lane < 16) ? wsum[lane] : 0;
#pragma unroll
            for (int off = 1; off < 16; off <<= 1) {
                int t = __shfl_up(ws, off, 64);
                if (lane >= off) ws += t;
            }
            if (lane < 16) wsum[lane] = ws;
        }
        __syncthreads();
        int wbase = (wid > 0) ? wsum[wid - 1] : 0;
        int incl = carry + wbase + s;
        if (i < n) rowptr[i + 1] = incl;
        __syncthreads();
        if (tid == 1023) carry = incl;   // = old carry + chunk total (OOB lanes add 0)
        __syncthreads();
    }
}

// ---------------- CSR bucket fill: csr_src[rowptr[dst]+k] = src ----------------

__global__ __launch_bounds__(256) void k_fill(const int* __restrict__ ei,
                                              const int* __restrict__ rowptr,
                                              int* __restrict__ cursor,
                                              int* __restrict__ csr_src, int e) {
    int i = blockIdx.x * 256 + threadIdx.x;
    if (i >= e) return;
    int s = ei[i];
    int d = ei[e + i];
    int pos = atomicAdd(&cursor[d], 1);
    csr_src[rowptr[d] + pos] = s;
}

// ---------------- GEMM: hs = (x @ W) * dinv[row]  (fp32, LDS tiled) ----------------

__device__ inline void fma4(float4& a, float s, const float4& w) {
    a.x = fmaf(s, w.x, a.x); a.y = fmaf(s, w.y, a.y);
    a.z = fmaf(s, w.z, a.z); a.w = fmaf(s, w.w, a.w);
}

__global__ __launch_bounds__(256) void k_gemm(const float* __restrict__ x,
                                              const float* __restrict__ W,
                                              const float* __restrict__ dinv,
                                              float* __restrict__ hs, int n) {
    __shared__ float sW[CH * CH];        // 64 KiB, row-major [k][c]
    __shared__ float sX[TM * 129];       // 64.5 KiB, pad 129

    const int tid = threadIdx.x;
    const int r0  = blockIdx.x * TM;

    const float4* W4 = (const float4*)W;
    float4* sW4 = (float4*)sW;
#pragma unroll
    for (int i = 0; i < 16; ++i) sW4[tid + i * 256] = W4[tid + i * 256];

#pragma unroll
    for (int i = 0; i < 16; ++i) {
        int f = tid + i * 256;
        int r = f >> 5, cq = f & 31;
        float4 v = make_float4(0.f, 0.f, 0.f, 0.f);
        if (r0 + r < n) v = ((const float4*)x)[(size_t)(r0 + r) * 32 + cq];
        float* d = &sX[r * 129 + cq * 4];
        d[0] = v.x; d[1] = v.y; d[2] = v.z; d[3] = v.w;
    }
    __syncthreads();

    const int cg = tid & 7;
    const int rbase = (tid >> 3) * 4;

    float4 acc[4][4];
#pragma unroll
    for (int i = 0; i < 4; ++i)
#pragma unroll
        for (int j = 0; j < 4; ++j) acc[i][j] = make_float4(0.f, 0.f, 0.f, 0.f);

#pragma unroll 4
    for (int k = 0; k < CH; ++k) {
        const float* wr = &sW[k * CH + cg * 4];
        float4 w0 = *(const float4*)(wr);
        float4 w1 = *(const float4*)(wr + 32);
        float4 w2 = *(const float4*)(wr + 64);
        float4 w3 = *(const float4*)(wr + 96);
#pragma unroll
        for (int i = 0; i < 4; ++i) {
            float xv = sX[(rbase + i) * 129 + k];
            fma4(acc[i][0], xv, w0);
            fma4(acc[i][1], xv, w1);
            fma4(acc[i][2], xv, w2);
            fma4(acc[i][3], xv, w3);
        }
    }

#pragma unroll
    for (int i = 0; i < 4; ++i) {
        int row = r0 + rbase + i;
        if (row < n) {
            float di = dinv[row];
            float4* hr = (float4*)(hs + (size_t)row * CH);
#pragma unroll
            for (int j = 0; j < 4; ++j) {
                float4 a = acc[i][j];
                a.x *= di; a.y *= di; a.z *= di; a.w *= di;
                hr[cg + 8 * j] = a;
            }
        }
    }
}

// ---------------- gather: out = relu(dinv[d] * (hs[d] + sum hs[src]) + b) ----------

__global__ __launch_bounds__(256) void k_gather(const float4* __restrict__ hs4,
                                                const int* __restrict__ rowptr,
                                                const int* __restrict__ csr_src,
                                                const float* __restrict__ dinv,
                                                const float4* __restrict__ b4,
                                                float4* __restrict__ out4, int n) {
    int idx  = blockIdx.x * 256 + threadIdx.x;
    int node = idx >> 5, lane = idx & 31;
    if (node >= n) return;

    float4 acc = hs4[(size_t)node * 32 + lane];   // self-loop term (pre-scaled by dinv[node])
    int beg = rowptr[node];
    int end = rowptr[node + 1];
    for (int j = beg; j < end; ++j) {
        int s = csr_src[j];
        float4 v = hs4[(size_t)s * 32 + lane];
        acc.x += v.x; acc.y += v.y; acc.z += v.z; acc.w += v.w;
    }
    float di = dinv[node];
    float4 bb = b4[lane];
    acc.x = fmaxf(fmaf(acc.x, di, bb.x), 0.f);
    acc.y = fmaxf(fmaf(acc.y, di, bb.y), 0.f);
    acc.z = fmaxf(fmaf(acc.z, di, bb.z), 0.f);
    acc.w = fmaxf(fmaf(acc.w, di, bb.w), 0.f);
    out4[idx] = acc;
}

// ---------------- fallback (ws too small): atomic scatter path ----------------

__global__ __launch_bounds__(256) void k_scatter_fb(const float4* __restrict__ hs4,
                                                    const int* __restrict__ ei,
                                                    const float* __restrict__ dinv,
                                                    float* __restrict__ out, int e) {
    int idx  = blockIdx.x * 256 + threadIdx.x;
    int edge = idx >> 5, lane = idx & 31;
    if (edge >= e) return;
    int s = ei[edge];
    int d = ei[e + edge];
    float nrm = dinv[d];                    // hs already carries dinv[s]
    float4 v = hs4[(size_t)s * 32 + lane];
    float* op = out + (size_t)d * CH + lane * 4;
    atomicAdd(op + 0, v.x * nrm);
    atomicAdd(op + 1, v.y * nrm);
    atomicAdd(op + 2, v.z * nrm);
    atomicAdd(op + 3, v.w * nrm);
}

__global__ __launch_bounds__(256) void k_finish_fb(float4* __restrict__ out4,
                                                   const float4* __restrict__ hs4,
                                                   const float* __restrict__ dinv,
                                                   const float4* __restrict__ b4,
                                                   int n) {
    int idx = blockIdx.x * 256 + threadIdx.x;
    if (idx >= n * 32) return;
    int node = idx >> 5, q = idx & 31;
    float di = dinv[node];
    float4 v = out4[idx];
    float4 hh = hs4[idx];
    float4 bb = b4[q];
    v.x = fmaxf(fmaf(hh.x, di, v.x) + bb.x, 0.f);
    v.y = fmaxf(fmaf(hh.y, di, v.y) + bb.y, 0.f);
    v.z = fmaxf(fmaf(hh.z, di, v.z) + bb.z, 0.f);
    v.w = fmaxf(fmaf(hh.w, di, v.w) + bb.w, 0.f);
    out4[idx] = v;
}

// ---------------- launch ----------------

extern "C" void kernel_launch(void* const* d_in, const int* in_sizes, int n_in,
                              void* d_out, int out_size, void* d_ws, size_t ws_size,
                              hipStream_t stream) {
    const float* x  = (const float*)d_in[0];
    const int*   ei = (const int*)d_in[1];
    const float* W  = (const float*)d_in[2];
    const float* b  = (const float*)d_in[3];
    float* out = (float*)d_out;

    const int N = in_sizes[0] / CH;     // 50000
    const int E = in_sizes[1] / 2;      // 800000

    // workspace layout
    size_t o_cnt    = 0;
    size_t o_dinv   = o_cnt    + align256((size_t)N * 4);
    size_t o_rowptr = o_dinv   + align256((size_t)N * 4);
    size_t o_cursor = o_rowptr + align256(((size_t)N + 1) * 4);
    size_t o_hs     = o_cursor + align256((size_t)N * 4);
    size_t o_csr    = o_hs     + align256((size_t)N * CH * 4);
    size_t need     = o_csr    + align256((size_t)E * 4);

    int*   cnt     = (int*)((char*)d_ws + o_cnt);
    float* dinv    = (float*)((char*)d_ws + o_dinv);
    int*   rowptr  = (int*)((char*)d_ws + o_rowptr);
    int*   cursor  = (int*)((char*)d_ws + o_cursor);
    float* hs      = (float*)((char*)d_ws + o_hs);
    int*   csr_src = (int*)((char*)d_ws + o_csr);

    const int gN  = (N + 255) / 256;
    const int gE  = (E + 255) / 256;
    const int gNL = ((N * 32) + 255) / 256;     // node*lane grids

    if (ws_size >= need) {
        hipMemsetAsync(cnt, 0, (size_t)N * 4, stream);
        hipMemsetAsync(cursor, 0, (size_t)N * 4, stream);
        k_hist<<<gE, 256, 0, stream>>>(ei + E, cnt, E);
        k_scan<<<1, 1024, 0, stream>>>(cnt, rowptr, N);
        k_dinv<<<gN, 256, 0, stream>>>(cnt, dinv, N);
        k_gemm<<<(N + TM - 1) / TM, 256, 0, stream>>>(x, W, dinv, hs, N);
        k_fill<<<gE, 256, 0, stream>>>(ei, rowptr, cursor, csr_src, E);
        k_gather<<<gNL, 256, 0, stream>>>((const float4*)hs, rowptr, csr_src, dinv,
                                          (const float4*)b, (float4*)out, N);
    } else {
        // fallback: atomic scatter (needs only cnt+dinv+hs)
        hipMemsetAsync(cnt, 0, (size_t)N * 4, stream);
        hipMemsetAsync(d_out, 0, (size_t)out_size * sizeof(float), stream);
        k_hist<<<gE, 256, 0, stream>>>(ei + E, cnt, E);
        k_dinv<<<gN, 256, 0, stream>>>(cnt, dinv, N);
        k_gemm<<<(N + TM - 1) / TM, 256, 0, stream>>>(x, W, dinv, hs, N);
        k_scatter_fb<<<(E * 32 + 255) / 256, 256, 0, stream>>>((const float4*)hs, ei, dinv, out, E);
        k_finish_fb<<<gNL, 256, 0, stream>>>((float4*)out, (const float4*)hs, dinv,
                                             (const float4*)b, N);
    }
}

// Round 3
// 163.889 us; speedup vs baseline: 8.8723x; 1.4823x over previous
//
#include <hip/hip_runtime.h>

#define CH 128          // IN_CH == OUT_CH == 128
#define GM 64           // rows per GEMM block
#define LDK 136         // padded K stride in LDS (bank-conflict-free, 16B-aligned rows)

typedef _Float16 f16x4 __attribute__((ext_vector_type(4)));
typedef float    f32x4 __attribute__((ext_vector_type(4)));
typedef unsigned short u16x8 __attribute__((ext_vector_type(8)));

static __host__ __device__ inline size_t align256(size_t x) { return (x + 255) & ~(size_t)255; }

__device__ inline unsigned short f2b(float f) {   // fp32 -> bf16 RNE
    unsigned int u = __float_as_uint(f);
    return (unsigned short)((u + 0x7fffu + ((u >> 16) & 1u)) >> 16);
}
__device__ inline float b2f(unsigned short h) {
    return __uint_as_float(((unsigned int)h) << 16);
}

// ---------------- degree histogram ----------------

__global__ __launch_bounds__(256) void k_hist(const int* __restrict__ dst,
                                              int* __restrict__ cnt, int e) {
    int i = blockIdx.x * 256 + threadIdx.x;
    if (i < e) atomicAdd(&cnt[dst[i]], 1);
}

// ---------------- hierarchical scan (3 kernels) + dinv fuse ----------------

__global__ __launch_bounds__(256) void k_scanb(const int* __restrict__ cnt,
                                               float* __restrict__ dinv,
                                               int* __restrict__ rowptr,   // temp: local inclusive at [i+1]
                                               int* __restrict__ partials, int n) {
    __shared__ int wsum[4];
    const int t = threadIdx.x, lane = t & 63, w = t >> 6;
    const int i = blockIdx.x * 256 + t;
    int v = (i < n) ? cnt[i] : 0;
    if (i < n) dinv[i] = rsqrtf((float)v + 1.0f);
    int s = v;
#pragma unroll
    for (int off = 1; off < 64; off <<= 1) {
        int tv = __shfl_up(s, off, 64);
        if (lane >= off) s += tv;
    }
    if (lane == 63) wsum[w] = s;
    __syncthreads();
    int wb = 0;
    for (int q = 0; q < w; ++q) wb += wsum[q];
    int incl = wb + s;
    if (i < n) rowptr[i + 1] = incl;
    if (t == 255) partials[blockIdx.x] = incl;   // block total (pad lanes add 0)
}

__global__ __launch_bounds__(256) void k_scanp(int* __restrict__ partials, int nb) {
    __shared__ int wsum[4];
    const int t = threadIdx.x, lane = t & 63, w = t >> 6;
    int v = (t < nb) ? partials[t] : 0;
    int s = v;
#pragma unroll
    for (int off = 1; off < 64; off <<= 1) {
        int tv = __shfl_up(s, off, 64);
        if (lane >= off) s += tv;
    }
    if (lane == 63) wsum[w] = s;
    __syncthreads();
    int wb = 0;
    for (int q = 0; q < w; ++q) wb += wsum[q];
    if (t < nb) partials[t] = wb + s - v;        // exclusive
}

__global__ __launch_bounds__(256) void k_scana(const int* __restrict__ cnt,
                                               int* __restrict__ rowptr,
                                               int* __restrict__ cursor,
                                               const int* __restrict__ partials, int n) {
    int i = blockIdx.x * 256 + threadIdx.x;
    if (i >= n) return;
    int off = partials[blockIdx.x];
    int incl = rowptr[i + 1] + off;
    rowptr[i + 1] = incl;
    cursor[i] = incl - cnt[i];                   // = exclusive scan = row start
    if (i == 0) rowptr[0] = 0;
}

// ---------------- CSR bucket fill ----------------

__global__ __launch_bounds__(256) void k_fill(const int* __restrict__ ei,
                                              int* __restrict__ cursor,
                                              int* __restrict__ csr_src, int e) {
    int i = blockIdx.x * 256 + threadIdx.x;
    if (i >= e) return;
    int s = ei[i];
    int d = ei[e + i];
    int pos = atomicAdd(&cursor[d], 1);
    csr_src[pos] = s;
}

// ---------------- W prep: fp32 [k][n] -> f16 bits transposed [n][k] ----------------

__global__ __launch_bounds__(256) void k_prepW(const float* __restrict__ W,
                                               unsigned short* __restrict__ WT) {
    int idx = blockIdx.x * 256 + threadIdx.x;   // 16384
    int k = idx >> 7, nn = idx & 127;
    _Float16 h = (_Float16)W[idx];
    WT[nn * CH + k] = *(unsigned short*)&h;
}

// ---------------- GEMM: hs_b = bf16( (x @ W) * dinv[row] )  via f16 MFMA ----------

__global__ __launch_bounds__(256) void k_gemm(const float* __restrict__ x,
                                              const unsigned short* __restrict__ WT,
                                              const float* __restrict__ dinv,
                                              unsigned short* __restrict__ hs_b, int n) {
    __shared__ unsigned short sA[GM * LDK];      // 17408 B
    __shared__ unsigned short sB[CH * LDK];      // 34816 B

    const int tid = threadIdx.x;
    const int r0  = blockIdx.x * GM;

    // stage B: WT row-major [n][128] -> sB [n][LDK], u16x8 chunks
    const u16x8* Wv = (const u16x8*)WT;
#pragma unroll
    for (int i = 0; i < 8; ++i) {
        int c = tid + i * 256;                   // 2048 chunks
        int nr = c >> 4, kq = c & 15;
        *(u16x8*)&sB[nr * LDK + kq * 8] = Wv[c];
    }

    // stage A: x fp32 -> f16, [r][LDK]
#pragma unroll
    for (int i = 0; i < 8; ++i) {
        int c = tid + i * 256;                   // 2048 float4 chunks
        int r = c >> 5, cq = c & 31;
        float4 v = make_float4(0.f, 0.f, 0.f, 0.f);
        if (r0 + r < n) v = ((const float4*)x)[(size_t)(r0 + r) * 32 + cq];
        f16x4 h;
        h[0] = (_Float16)v.x; h[1] = (_Float16)v.y;
        h[2] = (_Float16)v.z; h[3] = (_Float16)v.w;
        *(f16x4*)&sA[r * LDK + cq * 4] = h;
    }
    __syncthreads();

    const int lane = tid & 63, w = tid >> 6;
    const int mh = (w >> 1) * 32;                // wave's row-half
    const int nh = (w & 1) * 64;                 // wave's col-half
    const int fr = lane & 15, fg = lane >> 4;

    f32x4 acc[2][4];
#pragma unroll
    for (int a = 0; a < 2; ++a)
#pragma unroll
        for (int bq = 0; bq < 4; ++bq) acc[a][bq] = (f32x4){0.f, 0.f, 0.f, 0.f};

#pragma unroll
    for (int ks = 0; ks < 8; ++ks) {
        const int kk = ks * 16 + fg * 4;
        f16x4 a0 = *(const f16x4*)&sA[(mh + fr) * LDK + kk];
        f16x4 a1 = *(const f16x4*)&sA[(mh + 16 + fr) * LDK + kk];
        f16x4 b0 = *(const f16x4*)&sB[(nh + fr) * LDK + kk];
        f16x4 b1 = *(const f16x4*)&sB[(nh + 16 + fr) * LDK + kk];
        f16x4 b2 = *(const f16x4*)&sB[(nh + 32 + fr) * LDK + kk];
        f16x4 b3 = *(const f16x4*)&sB[(nh + 48 + fr) * LDK + kk];
        acc[0][0] = __builtin_amdgcn_mfma_f32_16x16x16f16(a0, b0, acc[0][0], 0, 0, 0);
        acc[0][1] = __builtin_amdgcn_mfma_f32_16x16x16f16(a0, b1, acc[0][1], 0, 0, 0);
        acc[0][2] = __builtin_amdgcn_mfma_f32_16x16x16f16(a0, b2, acc[0][2], 0, 0, 0);
        acc[0][3] = __builtin_amdgcn_mfma_f32_16x16x16f16(a0, b3, acc[0][3], 0, 0, 0);
        acc[1][0] = __builtin_amdgcn_mfma_f32_16x16x16f16(a1, b0, acc[1][0], 0, 0, 0);
        acc[1][1] = __builtin_amdgcn_mfma_f32_16x16x16f16(a1, b1, acc[1][1], 0, 0, 0);
        acc[1][2] = __builtin_amdgcn_mfma_f32_16x16x16f16(a1, b2, acc[1][2], 0, 0, 0);
        acc[1][3] = __builtin_amdgcn_mfma_f32_16x16x16f16(a1, b3, acc[1][3], 0, 0, 0);
    }

    // epilogue: hs_b[row][col] = bf16(acc * dinv[row])
#pragma unroll
    for (int mt = 0; mt < 2; ++mt) {
        int rbase = r0 + mh + mt * 16 + fg * 4;
        float dv[4];
#pragma unroll
        for (int rg = 0; rg < 4; ++rg)
            dv[rg] = (rbase + rg < n) ? dinv[rbase + rg] : 0.f;
#pragma unroll
        for (int nt = 0; nt < 4; ++nt) {
            int col = nh + nt * 16 + fr;
#pragma unroll
            for (int rg = 0; rg < 4; ++rg) {
                if (rbase + rg < n)
                    hs_b[(size_t)(rbase + rg) * CH + col] = f2b(acc[mt][nt][rg] * dv[rg]);
            }
        }
    }
}

// ---------------- gather: out = relu(dinv[d]*(hs[d] + sum hs[src]) + b) ------------
// 16 lanes per node, 16B bf16x8 loads, fp32 accumulate, 1-deep value prefetch.

__global__ __launch_bounds__(256) void k_gather(const u16x8* __restrict__ h8,
                                                const int* __restrict__ rowptr,
                                                const int* __restrict__ csr_src,
                                                const float* __restrict__ dinv,
                                                const float* __restrict__ bias,
                                                float* __restrict__ out, int n) {
    int idx  = blockIdx.x * 256 + threadIdx.x;
    int node = idx >> 4, lane = idx & 15;
    if (node >= n) return;

    float acc[8];
    {
        u16x8 v = h8[(size_t)node * 16 + lane];   // self term (pre-scaled by dinv[node])
#pragma unroll
        for (int i = 0; i < 8; ++i) acc[i] = b2f(v[i]);
    }

    int beg = rowptr[node];
    int end = rowptr[node + 1];
    if (beg < end) {
        u16x8 cur = h8[(size_t)csr_src[beg] * 16 + lane];
        for (int j = beg; j < end; ++j) {
            u16x8 v = cur;
            if (j + 1 < end) cur = h8[(size_t)csr_src[j + 1] * 16 + lane];
#pragma unroll
            for (int i = 0; i < 8; ++i) acc[i] += b2f(v[i]);
        }
    }

    float di = dinv[node];
    const float* bp = bias + lane * 8;
    float4 o0, o1;
    o0.x = fmaxf(fmaf(acc[0], di, bp[0]), 0.f);
    o0.y = fmaxf(fmaf(acc[1], di, bp[1]), 0.f);
    o0.z = fmaxf(fmaf(acc[2], di, bp[2]), 0.f);
    o0.w = fmaxf(fmaf(acc[3], di, bp[3]), 0.f);
    o1.x = fmaxf(fmaf(acc[4], di, bp[4]), 0.f);
    o1.y = fmaxf(fmaf(acc[5], di, bp[5]), 0.f);
    o1.z = fmaxf(fmaf(acc[6], di, bp[6]), 0.f);
    o1.w = fmaxf(fmaf(acc[7], di, bp[7]), 0.f);
    float4* op = (float4*)(out + (size_t)node * CH + lane * 8);
    op[0] = o0;
    op[1] = o1;
}

// ---------------- launch ----------------

extern "C" void kernel_launch(void* const* d_in, const int* in_sizes, int n_in,
                              void* d_out, int out_size, void* d_ws, size_t ws_size,
                              hipStream_t stream) {
    const float* x  = (const float*)d_in[0];
    const int*   ei = (const int*)d_in[1];
    const float* W  = (const float*)d_in[2];
    const float* b  = (const float*)d_in[3];
    float* out = (float*)d_out;

    const int N = in_sizes[0] / CH;     // 50000
    const int E = in_sizes[1] / 2;      // 800000

    const int NB = (N + 255) / 256;     // scan blocks (196)

    // workspace layout
    size_t o_cnt    = 0;
    size_t o_dinv   = o_cnt    + align256((size_t)N * 4);
    size_t o_rowptr = o_dinv   + align256((size_t)N * 4);
    size_t o_cursor = o_rowptr + align256(((size_t)N + 1) * 4);
    size_t o_part   = o_cursor + align256((size_t)N * 4);
    size_t o_WT     = o_part   + align256((size_t)NB * 4);
    size_t o_hs     = o_WT     + align256((size_t)CH * CH * 2);
    size_t o_csr    = o_hs     + align256((size_t)N * CH * 2);

    int*            cnt     = (int*)((char*)d_ws + o_cnt);
    float*          dinv    = (float*)((char*)d_ws + o_dinv);
    int*            rowptr  = (int*)((char*)d_ws + o_rowptr);
    int*            cursor  = (int*)((char*)d_ws + o_cursor);
    int*            part    = (int*)((char*)d_ws + o_part);
    unsigned short* WT      = (unsigned short*)((char*)d_ws + o_WT);
    unsigned short* hs_b    = (unsigned short*)((char*)d_ws + o_hs);
    int*            csr_src = (int*)((char*)d_ws + o_csr);

    const int gE = (E + 255) / 256;

    hipMemsetAsync(cnt, 0, (size_t)N * 4, stream);
    k_hist<<<gE, 256, 0, stream>>>(ei + E, cnt, E);
    k_scanb<<<NB, 256, 0, stream>>>(cnt, dinv, rowptr, part, N);
    k_scanp<<<1, 256, 0, stream>>>(part, NB);
    k_scana<<<NB, 256, 0, stream>>>(cnt, rowptr, cursor, part, N);
    k_prepW<<<(CH * CH) / 256, 256, 0, stream>>>(W, WT);
    k_gemm<<<(N + GM - 1) / GM, 256, 0, stream>>>(x, WT, dinv, hs_b, N);
    k_fill<<<gE, 256, 0, stream>>>(ei, cursor, csr_src, E);
    k_gather<<<(N * 16 + 255) / 256, 256, 0, stream>>>((const u16x8*)hs_b, rowptr, csr_src,
                                                       dinv, b, out, N);
}

// Round 4
// 107.664 us; speedup vs baseline: 13.5055x; 1.5222x over previous
//
#include <hip/hip_runtime.h>

#define CH 128          // IN_CH == OUT_CH == 128
#define GM 64           // rows per GEMM block
#define LDK 136         // padded K stride in LDS
#define BSH 7           // log2(nodes per bucket)
#define BNODES 128      // nodes per bucket
#define MAXB 512        // LDS array cap for buckets (NB=391 for N=50000)

typedef _Float16 f16x4 __attribute__((ext_vector_type(4)));
typedef float    f32x4 __attribute__((ext_vector_type(4)));
typedef unsigned short u16x8 __attribute__((ext_vector_type(8)));

static __host__ __device__ inline size_t align256(size_t x) { return (x + 255) & ~(size_t)255; }

__device__ inline unsigned short f2b(float f) {   // fp32 -> bf16 RNE
    unsigned int u = __float_as_uint(f);
    return (unsigned short)((u + 0x7fffu + ((u >> 16) & 1u)) >> 16);
}
__device__ inline float b2f(unsigned short h) {
    return __uint_as_float(((unsigned int)h) << 16);
}

// ---------------- bucket histogram (LDS-aggregated) ----------------

__global__ __launch_bounds__(256) void k_bhist(const int* __restrict__ dst,
                                               int* __restrict__ bcnt, int e, int nb) {
    __shared__ int l[MAXB];
    for (int i = threadIdx.x; i < nb; i += 256) l[i] = 0;
    __syncthreads();
    const int base = blockIdx.x * 4096;
    for (int i = threadIdx.x; i < 4096; i += 256) {
        int ed = base + i;
        if (ed < e) atomicAdd(&l[dst[ed] >> BSH], 1);
    }
    __syncthreads();
    for (int i = threadIdx.x; i < nb; i += 256)
        if (l[i]) atomicAdd(&bcnt[i], l[i]);
}

// ---------------- bucket scan (one block, Hillis-Steele) ----------------

__global__ __launch_bounds__(512) void k_bscan(const int* __restrict__ bcnt,
                                               int* __restrict__ boff,
                                               int* __restrict__ gcur, int nb) {
    __shared__ int buf[2][512];
    const int t = threadIdx.x;
    buf[0][t] = (t < nb) ? bcnt[t] : 0;
    __syncthreads();
    int cur = 0;
    for (int off = 1; off < 512; off <<= 1) {
        int val = buf[cur][t];
        if (t >= off) val += buf[cur][t - off];
        buf[cur ^ 1][t] = val;
        cur ^= 1;
        __syncthreads();
    }
    int excl = (t == 0) ? 0 : buf[cur][t - 1];
    if (t <= nb) boff[t] = excl;
    if (t < nb)  gcur[t] = excl;
}

// ---------------- bin edges into buckets, packed 4B: (src<<7)|(dst&127) --------

__global__ __launch_bounds__(256) void k_bin(const int* __restrict__ ei,
                                             int* __restrict__ gcur,
                                             unsigned int* __restrict__ pairs,
                                             int e, int nb) {
    __shared__ int lcnt[MAXB], lbase[MAXB], lpos[MAXB];
    const int t = threadIdx.x;
    for (int i = t; i < nb; i += 256) { lcnt[i] = 0; lpos[i] = 0; }
    __syncthreads();
    const int base = blockIdx.x * 4096;
    int s[16], d[16];
#pragma unroll
    for (int i = 0; i < 16; ++i) {
        int ed = base + t + i * 256;
        s[i] = -1; d[i] = 0;
        if (ed < e) {
            s[i] = ei[ed];
            d[i] = ei[e + ed];
            atomicAdd(&lcnt[d[i] >> BSH], 1);
        }
    }
    __syncthreads();
    for (int i = t; i < nb; i += 256)
        if (lcnt[i]) lbase[i] = atomicAdd(&gcur[i], lcnt[i]);
    __syncthreads();
#pragma unroll
    for (int i = 0; i < 16; ++i) {
        if (s[i] >= 0) {
            int b = d[i] >> BSH;
            int p = lbase[b] + atomicAdd(&lpos[b], 1);
            pairs[p] = ((unsigned)s[i] << BSH) | (unsigned)(d[i] & (BNODES - 1));
        }
    }
}

// ---------------- per-bucket CSR fill + rowptr + dinv (all LDS-local) ----------

__global__ __launch_bounds__(256) void k_fillb(const unsigned int* __restrict__ pairs,
                                               const int* __restrict__ boff,
                                               int* __restrict__ rowptr,
                                               float* __restrict__ dinv,
                                               int* __restrict__ csr_src, int n) {
    __shared__ int scnt[BNODES], sexcl[BNODES], scur[BNODES];
    const int t = threadIdx.x;
    const int b = blockIdx.x;
    const int n0 = b * BNODES;
    const int beg = boff[b], end = boff[b + 1];

    if (t < BNODES) scnt[t] = 0;
    __syncthreads();
    for (int j = beg + t; j < end; j += 256)
        atomicAdd(&scnt[pairs[j] & (BNODES - 1)], 1);
    __syncthreads();

    if (t < 64) {   // exclusive scan of 128 counts with one wave
        int c0 = scnt[t], c1 = scnt[t + 64];
        int s0 = c0, s1 = c1;
#pragma unroll
        for (int off = 1; off < 64; off <<= 1) {
            int t0 = __shfl_up(s0, off, 64);
            int t1 = __shfl_up(s1, off, 64);
            if (t >= off) { s0 += t0; s1 += t1; }
        }
        int tot0 = __shfl(s0, 63, 64);
        sexcl[t]      = s0 - c0;
        sexcl[t + 64] = tot0 + s1 - c1;
    }
    __syncthreads();

    if (t < BNODES) {
        int node = n0 + t;
        if (node < n) {
            rowptr[node + 1] = beg + sexcl[t] + scnt[t];
            dinv[node] = rsqrtf((float)scnt[t] + 1.0f);
        }
        scur[t] = sexcl[t];
    }
    if (b == 0 && t == 0) rowptr[0] = 0;
    __syncthreads();

    for (int j = beg + t; j < end; j += 256) {
        unsigned p = pairs[j];
        int pos = atomicAdd(&scur[p & (BNODES - 1)], 1);
        csr_src[beg + pos] = (int)(p >> BSH);
    }
}

// ---------------- W prep: fp32 [k][n] -> f16 bits transposed [n][k] ------------

__global__ __launch_bounds__(256) void k_prepW(const float* __restrict__ W,
                                               unsigned short* __restrict__ WT) {
    int idx = blockIdx.x * 256 + threadIdx.x;   // 16384
    int k = idx >> 7, nn = idx & 127;
    _Float16 h = (_Float16)W[idx];
    WT[nn * CH + k] = *(unsigned short*)&h;
}

// ---------------- GEMM: hs_b = bf16( (x @ W) * dinv[row] )  via f16 MFMA --------

__global__ __launch_bounds__(256) void k_gemm(const float* __restrict__ x,
                                              const unsigned short* __restrict__ WT,
                                              const float* __restrict__ dinv,
                                              unsigned short* __restrict__ hs_b, int n) {
    __shared__ unsigned short sA[GM * LDK];
    __shared__ unsigned short sB[CH * LDK];

    const int tid = threadIdx.x;
    const int r0  = blockIdx.x * GM;

    const u16x8* Wv = (const u16x8*)WT;
#pragma unroll
    for (int i = 0; i < 8; ++i) {
        int c = tid + i * 256;
        int nr = c >> 4, kq = c & 15;
        *(u16x8*)&sB[nr * LDK + kq * 8] = Wv[c];
    }
#pragma unroll
    for (int i = 0; i < 8; ++i) {
        int c = tid + i * 256;
        int r = c >> 5, cq = c & 31;
        float4 v = make_float4(0.f, 0.f, 0.f, 0.f);
        if (r0 + r < n) v = ((const float4*)x)[(size_t)(r0 + r) * 32 + cq];
        f16x4 h;
        h[0] = (_Float16)v.x; h[1] = (_Float16)v.y;
        h[2] = (_Float16)v.z; h[3] = (_Float16)v.w;
        *(f16x4*)&sA[r * LDK + cq * 4] = h;
    }
    __syncthreads();

    const int lane = tid & 63, w = tid >> 6;
    const int mh = (w >> 1) * 32;
    const int nh = (w & 1) * 64;
    const int fr = lane & 15, fg = lane >> 4;

    f32x4 acc[2][4];
#pragma unroll
    for (int a = 0; a < 2; ++a)
#pragma unroll
        for (int bq = 0; bq < 4; ++bq) acc[a][bq] = (f32x4){0.f, 0.f, 0.f, 0.f};

#pragma unroll
    for (int ks = 0; ks < 8; ++ks) {
        const int kk = ks * 16 + fg * 4;
        f16x4 a0 = *(const f16x4*)&sA[(mh + fr) * LDK + kk];
        f16x4 a1 = *(const f16x4*)&sA[(mh + 16 + fr) * LDK + kk];
        f16x4 b0 = *(const f16x4*)&sB[(nh + fr) * LDK + kk];
        f16x4 b1 = *(const f16x4*)&sB[(nh + 16 + fr) * LDK + kk];
        f16x4 b2 = *(const f16x4*)&sB[(nh + 32 + fr) * LDK + kk];
        f16x4 b3 = *(const f16x4*)&sB[(nh + 48 + fr) * LDK + kk];
        acc[0][0] = __builtin_amdgcn_mfma_f32_16x16x16f16(a0, b0, acc[0][0], 0, 0, 0);
        acc[0][1] = __builtin_amdgcn_mfma_f32_16x16x16f16(a0, b1, acc[0][1], 0, 0, 0);
        acc[0][2] = __builtin_amdgcn_mfma_f32_16x16x16f16(a0, b2, acc[0][2], 0, 0, 0);
        acc[0][3] = __builtin_amdgcn_mfma_f32_16x16x16f16(a0, b3, acc[0][3], 0, 0, 0);
        acc[1][0] = __builtin_amdgcn_mfma_f32_16x16x16f16(a1, b0, acc[1][0], 0, 0, 0);
        acc[1][1] = __builtin_amdgcn_mfma_f32_16x16x16f16(a1, b1, acc[1][1], 0, 0, 0);
        acc[1][2] = __builtin_amdgcn_mfma_f32_16x16x16f16(a1, b2, acc[1][2], 0, 0, 0);
        acc[1][3] = __builtin_amdgcn_mfma_f32_16x16x16f16(a1, b3, acc[1][3], 0, 0, 0);
    }

#pragma unroll
    for (int mt = 0; mt < 2; ++mt) {
        int rbase = r0 + mh + mt * 16 + fg * 4;
        float dv[4];
#pragma unroll
        for (int rg = 0; rg < 4; ++rg)
            dv[rg] = (rbase + rg < n) ? dinv[rbase + rg] : 0.f;
#pragma unroll
        for (int nt = 0; nt < 4; ++nt) {
            int col = nh + nt * 16 + fr;
#pragma unroll
            for (int rg = 0; rg < 4; ++rg) {
                if (rbase + rg < n)
                    hs_b[(size_t)(rbase + rg) * CH + col] = f2b(acc[mt][nt][rg] * dv[rg]);
            }
        }
    }
}

// ---------------- gather: out = relu(dinv[d]*(hs[d] + sum hs[src]) + b) --------

__global__ __launch_bounds__(256) void k_gather(const u16x8* __restrict__ h8,
                                                const int* __restrict__ rowptr,
                                                const int* __restrict__ csr_src,
                                                const float* __restrict__ dinv,
                                                const float* __restrict__ bias,
                                                float* __restrict__ out, int n) {
    int idx  = blockIdx.x * 256 + threadIdx.x;
    int node = idx >> 4, lane = idx & 15;
    if (node >= n) return;

    float acc[8];
    {
        u16x8 v = h8[(size_t)node * 16 + lane];
#pragma unroll
        for (int i = 0; i < 8; ++i) acc[i] = b2f(v[i]);
    }

    int beg = rowptr[node];
    int end = rowptr[node + 1];
    if (beg < end) {
        u16x8 cur = h8[(size_t)csr_src[beg] * 16 + lane];
        for (int j = beg; j < end; ++j) {
            u16x8 v = cur;
            if (j + 1 < end) cur = h8[(size_t)csr_src[j + 1] * 16 + lane];
#pragma unroll
            for (int i = 0; i < 8; ++i) acc[i] += b2f(v[i]);
        }
    }

    float di = dinv[node];
    const float* bp = bias + lane * 8;
    float4 o0, o1;
    o0.x = fmaxf(fmaf(acc[0], di, bp[0]), 0.f);
    o0.y = fmaxf(fmaf(acc[1], di, bp[1]), 0.f);
    o0.z = fmaxf(fmaf(acc[2], di, bp[2]), 0.f);
    o0.w = fmaxf(fmaf(acc[3], di, bp[3]), 0.f);
    o1.x = fmaxf(fmaf(acc[4], di, bp[4]), 0.f);
    o1.y = fmaxf(fmaf(acc[5], di, bp[5]), 0.f);
    o1.z = fmaxf(fmaf(acc[6], di, bp[6]), 0.f);
    o1.w = fmaxf(fmaf(acc[7], di, bp[7]), 0.f);
    float4* op = (float4*)(out + (size_t)node * CH + lane * 8);
    op[0] = o0;
    op[1] = o1;
}

// ---------------- launch ----------------

extern "C" void kernel_launch(void* const* d_in, const int* in_sizes, int n_in,
                              void* d_out, int out_size, void* d_ws, size_t ws_size,
                              hipStream_t stream) {
    const float* x  = (const float*)d_in[0];
    const int*   ei = (const int*)d_in[1];
    const float* W  = (const float*)d_in[2];
    const float* b  = (const float*)d_in[3];
    float* out = (float*)d_out;

    const int N = in_sizes[0] / CH;     // 50000  (src ids < 65536 -> 4B packing valid)
    const int E = in_sizes[1] / 2;      // 800000

    const int NB = (N + BNODES - 1) / BNODES;   // 391 buckets

    // workspace layout
    size_t o_bcnt   = 0;
    size_t o_boff   = o_bcnt   + align256((size_t)NB * 4);
    size_t o_gcur   = o_boff   + align256(((size_t)NB + 1) * 4);
    size_t o_dinv   = o_gcur   + align256((size_t)NB * 4);
    size_t o_rowptr = o_dinv   + align256((size_t)N * 4);
    size_t o_WT     = o_rowptr + align256(((size_t)N + 1) * 4);
    size_t o_hs     = o_WT     + align256((size_t)CH * CH * 2);
    size_t o_pairs  = o_hs     + align256((size_t)N * CH * 2);
    size_t o_csr    = o_pairs  + align256((size_t)E * 4);

    int*            bcnt    = (int*)((char*)d_ws + o_bcnt);
    int*            boff    = (int*)((char*)d_ws + o_boff);
    int*            gcur    = (int*)((char*)d_ws + o_gcur);
    float*          dinv    = (float*)((char*)d_ws + o_dinv);
    int*            rowptr  = (int*)((char*)d_ws + o_rowptr);
    unsigned short* WT      = (unsigned short*)((char*)d_ws + o_WT);
    unsigned short* hs_b    = (unsigned short*)((char*)d_ws + o_hs);
    unsigned int*   pairs   = (unsigned int*)((char*)d_ws + o_pairs);
    int*            csr_src = (int*)((char*)d_ws + o_csr);

    const int gCH = (E + 4095) / 4096;          // 4096-edge chunks

    hipMemsetAsync(bcnt, 0, (size_t)NB * 4, stream);
    k_bhist<<<gCH, 256, 0, stream>>>(ei + E, bcnt, E, NB);
    k_bscan<<<1, 512, 0, stream>>>(bcnt, boff, gcur, NB);
    k_bin<<<gCH, 256, 0, stream>>>(ei, gcur, pairs, E, NB);
    k_fillb<<<NB, 256, 0, stream>>>(pairs, boff, rowptr, dinv, csr_src, N);
    k_prepW<<<(CH * CH) / 256, 256, 0, stream>>>(W, WT);
    k_gemm<<<(N + GM - 1) / GM, 256, 0, stream>>>(x, WT, dinv, hs_b, N);
    k_gather<<<(N * 16 + 255) / 256, 256, 0, stream>>>((const u16x8*)hs_b, rowptr, csr_src,
                                                       dinv, b, out, N);
}

// Round 5
// 107.490 us; speedup vs baseline: 13.5274x; 1.0016x over previous
//
#include <hip/hip_runtime.h>

#define CH 128          // IN_CH == OUT_CH == 128
#define GM 64           // rows per GEMM block
#define LDK 136         // padded K stride in LDS
#define BSH 7           // log2(nodes per bucket)
#define BNODES 128      // nodes per bucket
#define MAXB 512        // LDS array cap for buckets (NB=391 for N=50000)

typedef _Float16 f16x4 __attribute__((ext_vector_type(4)));
typedef float    f32x4 __attribute__((ext_vector_type(4)));
typedef unsigned short u16x8 __attribute__((ext_vector_type(8)));

static __host__ __device__ inline size_t align256(size_t x) { return (x + 255) & ~(size_t)255; }

__device__ inline unsigned short f2b(float f) {   // fp32 -> bf16 RNE
    unsigned int u = __float_as_uint(f);
    return (unsigned short)((u + 0x7fffu + ((u >> 16) & 1u)) >> 16);
}
__device__ inline float b2f(unsigned short h) {
    return __uint_as_float(((unsigned int)h) << 16);
}

// ---------------- bucket histogram (LDS-aggregated) ----------------

__global__ __launch_bounds__(256) void k_bhist(const int* __restrict__ dst,
                                               int* __restrict__ bcnt, int e, int nb) {
    __shared__ int l[MAXB];
    for (int i = threadIdx.x; i < nb; i += 256) l[i] = 0;
    __syncthreads();
    const int base = blockIdx.x * 4096;
    for (int i = threadIdx.x; i < 4096; i += 256) {
        int ed = base + i;
        if (ed < e) atomicAdd(&l[dst[ed] >> BSH], 1);
    }
    __syncthreads();
    for (int i = threadIdx.x; i < nb; i += 256)
        if (l[i]) atomicAdd(&bcnt[i], l[i]);
}

// ---------------- bucket scan (one block) + W f16-transpose fused ----------------

__global__ __launch_bounds__(512) void k_bscan(const int* __restrict__ bcnt,
                                               int* __restrict__ boff,
                                               int* __restrict__ gcur, int nb,
                                               const float* __restrict__ W,
                                               unsigned short* __restrict__ WT) {
    const int t = threadIdx.x;
    // fused W prep: fp32 [k][n] -> f16 bits transposed [n][k] (16384 elems)
#pragma unroll
    for (int i = 0; i < 32; ++i) {
        int idx = t + i * 512;
        int k = idx >> 7, nn = idx & 127;
        _Float16 h = (_Float16)W[idx];
        WT[nn * CH + k] = *(unsigned short*)&h;
    }
    // Hillis-Steele scan of bucket counts
    __shared__ int buf[2][512];
    buf[0][t] = (t < nb) ? bcnt[t] : 0;
    __syncthreads();
    int cur = 0;
    for (int off = 1; off < 512; off <<= 1) {
        int val = buf[cur][t];
        if (t >= off) val += buf[cur][t - off];
        buf[cur ^ 1][t] = val;
        cur ^= 1;
        __syncthreads();
    }
    int excl = (t == 0) ? 0 : buf[cur][t - 1];
    if (t <= nb) boff[t] = excl;
    if (t < nb)  gcur[t] = excl;
}

// ---------------- bin edges into buckets, packed 4B: (src<<7)|(dst&127) --------

__global__ __launch_bounds__(256) void k_bin(const int* __restrict__ ei,
                                             int* __restrict__ gcur,
                                             unsigned int* __restrict__ pairs,
                                             int e, int nb) {
    __shared__ int lcnt[MAXB], lbase[MAXB], lpos[MAXB];
    const int t = threadIdx.x;
    for (int i = t; i < nb; i += 256) { lcnt[i] = 0; lpos[i] = 0; }
    __syncthreads();
    const int base = blockIdx.x * 4096;
    int s[16], d[16];
#pragma unroll
    for (int i = 0; i < 16; ++i) {
        int ed = base + t + i * 256;
        s[i] = -1; d[i] = 0;
        if (ed < e) {
            s[i] = ei[ed];
            d[i] = ei[e + ed];
            atomicAdd(&lcnt[d[i] >> BSH], 1);
        }
    }
    __syncthreads();
    for (int i = t; i < nb; i += 256)
        if (lcnt[i]) lbase[i] = atomicAdd(&gcur[i], lcnt[i]);
    __syncthreads();
#pragma unroll
    for (int i = 0; i < 16; ++i) {
        if (s[i] >= 0) {
            int b = d[i] >> BSH;
            int p = lbase[b] + atomicAdd(&lpos[b], 1);
            pairs[p] = ((unsigned)s[i] << BSH) | (unsigned)(d[i] & (BNODES - 1));
        }
    }
}

// ---------------- per-bucket CSR fill + rowptr + dinv (all LDS-local) ----------

__global__ __launch_bounds__(256) void k_fillb(const unsigned int* __restrict__ pairs,
                                               const int* __restrict__ boff,
                                               int* __restrict__ rowptr,
                                               float* __restrict__ dinv,
                                               int* __restrict__ csr_src, int n) {
    __shared__ int scnt[BNODES], sexcl[BNODES], scur[BNODES];
    const int t = threadIdx.x;
    const int b = blockIdx.x;
    const int n0 = b * BNODES;
    const int beg = boff[b], end = boff[b + 1];

    if (t < BNODES) scnt[t] = 0;
    __syncthreads();
    for (int j = beg + t; j < end; j += 256)
        atomicAdd(&scnt[pairs[j] & (BNODES - 1)], 1);
    __syncthreads();

    if (t < 64) {   // exclusive scan of 128 counts with one wave
        int c0 = scnt[t], c1 = scnt[t + 64];
        int s0 = c0, s1 = c1;
#pragma unroll
        for (int off = 1; off < 64; off <<= 1) {
            int t0 = __shfl_up(s0, off, 64);
            int t1 = __shfl_up(s1, off, 64);
            if (t >= off) { s0 += t0; s1 += t1; }
        }
        int tot0 = __shfl(s0, 63, 64);
        sexcl[t]      = s0 - c0;
        sexcl[t + 64] = tot0 + s1 - c1;
    }
    __syncthreads();

    if (t < BNODES) {
        int node = n0 + t;
        if (node < n) {
            rowptr[node + 1] = beg + sexcl[t] + scnt[t];
            dinv[node] = rsqrtf((float)scnt[t] + 1.0f);
        }
        scur[t] = sexcl[t];
    }
    if (b == 0 && t == 0) rowptr[0] = 0;
    __syncthreads();

    for (int j = beg + t; j < end; j += 256) {
        unsigned p = pairs[j];
        int pos = atomicAdd(&scur[p & (BNODES - 1)], 1);
        csr_src[beg + pos] = (int)(p >> BSH);
    }
}

// ---------------- GEMM: hs_b = bf16( (x @ W) * dinv[row] )  via f16 MFMA --------

__global__ __launch_bounds__(256) void k_gemm(const float* __restrict__ x,
                                              const unsigned short* __restrict__ WT,
                                              const float* __restrict__ dinv,
                                              unsigned short* __restrict__ hs_b, int n) {
    __shared__ unsigned short sA[GM * LDK];
    __shared__ unsigned short sB[CH * LDK];

    const int tid = threadIdx.x;
    const int r0  = blockIdx.x * GM;

    const u16x8* Wv = (const u16x8*)WT;
#pragma unroll
    for (int i = 0; i < 8; ++i) {
        int c = tid + i * 256;
        int nr = c >> 4, kq = c & 15;
        *(u16x8*)&sB[nr * LDK + kq * 8] = Wv[c];
    }
#pragma unroll
    for (int i = 0; i < 8; ++i) {
        int c = tid + i * 256;
        int r = c >> 5, cq = c & 31;
        float4 v = make_float4(0.f, 0.f, 0.f, 0.f);
        if (r0 + r < n) v = ((const float4*)x)[(size_t)(r0 + r) * 32 + cq];
        f16x4 h;
        h[0] = (_Float16)v.x; h[1] = (_Float16)v.y;
        h[2] = (_Float16)v.z; h[3] = (_Float16)v.w;
        *(f16x4*)&sA[r * LDK + cq * 4] = h;
    }
    __syncthreads();

    const int lane = tid & 63, w = tid >> 6;
    const int mh = (w >> 1) * 32;
    const int nh = (w & 1) * 64;
    const int fr = lane & 15, fg = lane >> 4;

    f32x4 acc[2][4];
#pragma unroll
    for (int a = 0; a < 2; ++a)
#pragma unroll
        for (int bq = 0; bq < 4; ++bq) acc[a][bq] = (f32x4){0.f, 0.f, 0.f, 0.f};

#pragma unroll
    for (int ks = 0; ks < 8; ++ks) {
        const int kk = ks * 16 + fg * 4;
        f16x4 a0 = *(const f16x4*)&sA[(mh + fr) * LDK + kk];
        f16x4 a1 = *(const f16x4*)&sA[(mh + 16 + fr) * LDK + kk];
        f16x4 b0 = *(const f16x4*)&sB[(nh + fr) * LDK + kk];
        f16x4 b1 = *(const f16x4*)&sB[(nh + 16 + fr) * LDK + kk];
        f16x4 b2 = *(const f16x4*)&sB[(nh + 32 + fr) * LDK + kk];
        f16x4 b3 = *(const f16x4*)&sB[(nh + 48 + fr) * LDK + kk];
        acc[0][0] = __builtin_amdgcn_mfma_f32_16x16x16f16(a0, b0, acc[0][0], 0, 0, 0);
        acc[0][1] = __builtin_amdgcn_mfma_f32_16x16x16f16(a0, b1, acc[0][1], 0, 0, 0);
        acc[0][2] = __builtin_amdgcn_mfma_f32_16x16x16f16(a0, b2, acc[0][2], 0, 0, 0);
        acc[0][3] = __builtin_amdgcn_mfma_f32_16x16x16f16(a0, b3, acc[0][3], 0, 0, 0);
        acc[1][0] = __builtin_amdgcn_mfma_f32_16x16x16f16(a1, b0, acc[1][0], 0, 0, 0);
        acc[1][1] = __builtin_amdgcn_mfma_f32_16x16x16f16(a1, b1, acc[1][1], 0, 0, 0);
        acc[1][2] = __builtin_amdgcn_mfma_f32_16x16x16f16(a1, b2, acc[1][2], 0, 0, 0);
        acc[1][3] = __builtin_amdgcn_mfma_f32_16x16x16f16(a1, b3, acc[1][3], 0, 0, 0);
    }

#pragma unroll
    for (int mt = 0; mt < 2; ++mt) {
        int rbase = r0 + mh + mt * 16 + fg * 4;
        float dv[4];
#pragma unroll
        for (int rg = 0; rg < 4; ++rg)
            dv[rg] = (rbase + rg < n) ? dinv[rbase + rg] : 0.f;
#pragma unroll
        for (int nt = 0; nt < 4; ++nt) {
            int col = nh + nt * 16 + fr;
#pragma unroll
            for (int rg = 0; rg < 4; ++rg) {
                if (rbase + rg < n)
                    hs_b[(size_t)(rbase + rg) * CH + col] = f2b(acc[mt][nt][rg] * dv[rg]);
            }
        }
    }
}

// ---------------- gather: out = relu(dinv[d]*(hs[d] + sum hs[src]) + b) --------
// 16 lanes per node; 4-deep unrolled row loads for MLP; fp32 accumulate.

__global__ __launch_bounds__(256) void k_gather(const u16x8* __restrict__ h8,
                                                const int* __restrict__ rowptr,
                                                const int* __restrict__ csr_src,
                                                const float* __restrict__ dinv,
                                                const float* __restrict__ bias,
                                                float* __restrict__ out, int n) {
    int idx  = blockIdx.x * 256 + threadIdx.x;
    int node = idx >> 4, lane = idx & 15;
    if (node >= n) return;

    float acc[8];
    {
        u16x8 v = h8[(size_t)node * 16 + lane];
#pragma unroll
        for (int i = 0; i < 8; ++i) acc[i] = b2f(v[i]);
    }

    int j = rowptr[node];
    const int end = rowptr[node + 1];

    for (; j + 4 <= end; j += 4) {
        int s0 = csr_src[j + 0];
        int s1 = csr_src[j + 1];
        int s2 = csr_src[j + 2];
        int s3 = csr_src[j + 3];
        u16x8 v0 = h8[(size_t)s0 * 16 + lane];
        u16x8 v1 = h8[(size_t)s1 * 16 + lane];
        u16x8 v2 = h8[(size_t)s2 * 16 + lane];
        u16x8 v3 = h8[(size_t)s3 * 16 + lane];
#pragma unroll
        for (int i = 0; i < 8; ++i)
            acc[i] += (b2f(v0[i]) + b2f(v1[i])) + (b2f(v2[i]) + b2f(v3[i]));
    }
    for (; j < end; ++j) {
        u16x8 v = h8[(size_t)csr_src[j] * 16 + lane];
#pragma unroll
        for (int i = 0; i < 8; ++i) acc[i] += b2f(v[i]);
    }

    float di = dinv[node];
    const float* bp = bias + lane * 8;
    float4 o0, o1;
    o0.x = fmaxf(fmaf(acc[0], di, bp[0]), 0.f);
    o0.y = fmaxf(fmaf(acc[1], di, bp[1]), 0.f);
    o0.z = fmaxf(fmaf(acc[2], di, bp[2]), 0.f);
    o0.w = fmaxf(fmaf(acc[3], di, bp[3]), 0.f);
    o1.x = fmaxf(fmaf(acc[4], di, bp[4]), 0.f);
    o1.y = fmaxf(fmaf(acc[5], di, bp[5]), 0.f);
    o1.z = fmaxf(fmaf(acc[6], di, bp[6]), 0.f);
    o1.w = fmaxf(fmaf(acc[7], di, bp[7]), 0.f);
    float4* op = (float4*)(out + (size_t)node * CH + lane * 8);
    op[0] = o0;
    op[1] = o1;
}

// ---------------- launch ----------------

extern "C" void kernel_launch(void* const* d_in, const int* in_sizes, int n_in,
                              void* d_out, int out_size, void* d_ws, size_t ws_size,
                              hipStream_t stream) {
    const float* x  = (const float*)d_in[0];
    const int*   ei = (const int*)d_in[1];
    const float* W  = (const float*)d_in[2];
    const float* b  = (const float*)d_in[3];
    float* out = (float*)d_out;

    const int N = in_sizes[0] / CH;     // 50000  (src ids < 65536 -> 4B packing valid)
    const int E = in_sizes[1] / 2;      // 800000

    const int NB = (N + BNODES - 1) / BNODES;   // 391 buckets

    // workspace layout
    size_t o_bcnt   = 0;
    size_t o_boff   = o_bcnt   + align256((size_t)NB * 4);
    size_t o_gcur   = o_boff   + align256(((size_t)NB + 1) * 4);
    size_t o_dinv   = o_gcur   + align256((size_t)NB * 4);
    size_t o_rowptr = o_dinv   + align256((size_t)N * 4);
    size_t o_WT     = o_rowptr + align256(((size_t)N + 1) * 4);
    size_t o_hs     = o_WT     + align256((size_t)CH * CH * 2);
    size_t o_pairs  = o_hs     + align256((size_t)N * CH * 2);
    size_t o_csr    = o_pairs  + align256((size_t)E * 4);

    int*            bcnt    = (int*)((char*)d_ws + o_bcnt);
    int*            boff    = (int*)((char*)d_ws + o_boff);
    int*            gcur    = (int*)((char*)d_ws + o_gcur);
    float*          dinv    = (float*)((char*)d_ws + o_dinv);
    int*            rowptr  = (int*)((char*)d_ws + o_rowptr);
    unsigned short* WT      = (unsigned short*)((char*)d_ws + o_WT);
    unsigned short* hs_b    = (unsigned short*)((char*)d_ws + o_hs);
    unsigned int*   pairs   = (unsigned int*)((char*)d_ws + o_pairs);
    int*            csr_src = (int*)((char*)d_ws + o_csr);

    const int gCH = (E + 4095) / 4096;          // 4096-edge chunks

    hipMemsetAsync(bcnt, 0, (size_t)NB * 4, stream);
    k_bhist<<<gCH, 256, 0, stream>>>(ei + E, bcnt, E, NB);
    k_bscan<<<1, 512, 0, stream>>>(bcnt, boff, gcur, NB, W, WT);
    k_bin<<<gCH, 256, 0, stream>>>(ei, gcur, pairs, E, NB);
    k_fillb<<<NB, 256, 0, stream>>>(pairs, boff, rowptr, dinv, csr_src, N);
    k_gemm<<<(N + GM - 1) / GM, 256, 0, stream>>>(x, WT, dinv, hs_b, N);
    k_gather<<<(N * 16 + 255) / 256, 256, 0, stream>>>((const u16x8*)hs_b, rowptr, csr_src,
                                                       dinv, b, out, N);
}

// Round 6
// 84.159 us; speedup vs baseline: 17.2776x; 1.2772x over previous
//
#include <hip/hip_runtime.h>

#define CH 128          // IN_CH == OUT_CH == 128
#define GM 64           // rows per GEMM block
#define LDK 136         // padded K stride in LDS
#define BSH 6           // log2(nodes per bucket)
#define BNODES 64       // nodes per bucket
#define CAP 3072        // per-bucket pair capacity (Poisson lambda=1024; spill handles excess)
#define MAXB 1024       // LDS cap for bucket arrays (NB=782 for N=50000)

typedef _Float16 f16x4 __attribute__((ext_vector_type(4)));
typedef float    f32x4 __attribute__((ext_vector_type(4)));
typedef unsigned short u16x8 __attribute__((ext_vector_type(8)));

static __host__ __device__ inline size_t align256(size_t x) { return (x + 255) & ~(size_t)255; }

__device__ inline unsigned short f2b(float f) {   // fp32 -> bf16 RNE
    unsigned int u = __float_as_uint(f);
    return (unsigned short)((u + 0x7fffu + ((u >> 16) & 1u)) >> 16);
}
__device__ inline float b2f(unsigned short h) {
    return __uint_as_float(((unsigned int)h) << 16);
}

// ---------------- bin edges into fixed-capacity buckets + W f16-transpose --------
// pairs[b*CAP + slot] = (src<<6)|(dst&63).  Overflow -> spill list (normally empty).

__global__ __launch_bounds__(256) void k_bin(const int* __restrict__ ei,
                                             int* __restrict__ gcur,      // [nb+1]; [nb]=spill cnt
                                             unsigned int* __restrict__ pairs,
                                             unsigned int* __restrict__ spill,
                                             int e, int nb,
                                             const float* __restrict__ W,
                                             unsigned short* __restrict__ WT) {
    __shared__ int lcnt[MAXB], lbase[MAXB], lpos[MAXB];
    const int t = threadIdx.x;

    // fused W prep: fp32 [k][n] -> f16 bits transposed [n][k]; first 8 blocks
    if (blockIdx.x < 8) {
        int wb = blockIdx.x * 2048;
#pragma unroll
        for (int i = 0; i < 8; ++i) {
            int idx = wb + t + i * 256;
            int k = idx >> 7, nn = idx & 127;
            _Float16 h = (_Float16)W[idx];
            WT[nn * CH + k] = *(unsigned short*)&h;
        }
    }

    for (int i = t; i < nb; i += 256) { lcnt[i] = 0; lpos[i] = 0; }
    __syncthreads();

    const int base = blockIdx.x * 4096;
    int s[16], d[16];
#pragma unroll
    for (int i = 0; i < 16; ++i) {
        int ed = base + t + i * 256;
        s[i] = -1; d[i] = 0;
        if (ed < e) {
            s[i] = ei[ed];
            d[i] = ei[e + ed];
            atomicAdd(&lcnt[d[i] >> BSH], 1);
        }
    }
    __syncthreads();
    for (int i = t; i < nb; i += 256)
        if (lcnt[i]) lbase[i] = atomicAdd(&gcur[i], lcnt[i]);
    __syncthreads();
#pragma unroll
    for (int i = 0; i < 16; ++i) {
        if (s[i] >= 0) {
            int b = d[i] >> BSH;
            int p = lbase[b] + atomicAdd(&lpos[b], 1);
            if (p < CAP) {
                pairs[(size_t)b * CAP + p] = ((unsigned)s[i] << BSH) | (unsigned)(d[i] & (BNODES - 1));
            } else {
                int sp = atomicAdd(&gcur[nb], 1);
                spill[sp] = ((unsigned)s[i] << 16) | (unsigned)d[i];
            }
        }
    }
}

// ---------------- per-bucket degree count -> dinv ----------------

__global__ __launch_bounds__(256) void k_cnt(const unsigned int* __restrict__ pairs,
                                             const int* __restrict__ gcur,
                                             const unsigned int* __restrict__ spill,
                                             float* __restrict__ dinv, int n, int nb) {
    __shared__ int scnt[BNODES];
    const int t = threadIdx.x, b = blockIdx.x;
    if (t < BNODES) scnt[t] = 0;
    __syncthreads();
    const int cntb = min(gcur[b], CAP);
    const unsigned int* pp = pairs + (size_t)b * CAP;
    for (int j = t; j < cntb; j += 256)
        atomicAdd(&scnt[pp[j] & (BNODES - 1)], 1);
    const int ns = gcur[nb];
    if (ns > 0) {     // cold path: spilled edges
        for (int j = t; j < ns; j += 256) {
            unsigned u = spill[j];
            unsigned dd = u & 0xffffu;
            if ((int)(dd >> BSH) == b) atomicAdd(&scnt[dd & (BNODES - 1)], 1);
        }
    }
    __syncthreads();
    int node = b * BNODES + t;
    if (t < BNODES && node < n)
        dinv[node] = rsqrtf((float)scnt[t] + 1.0f);
}

// ---------------- GEMM: hs_b = bf16( (x @ W) * dinv[row] )  via f16 MFMA --------

__global__ __launch_bounds__(256) void k_gemm(const float* __restrict__ x,
                                              const unsigned short* __restrict__ WT,
                                              const float* __restrict__ dinv,
                                              unsigned short* __restrict__ hs_b, int n) {
    __shared__ unsigned short sA[GM * LDK];
    __shared__ unsigned short sB[CH * LDK];

    const int tid = threadIdx.x;
    const int r0  = blockIdx.x * GM;

    const u16x8* Wv = (const u16x8*)WT;
#pragma unroll
    for (int i = 0; i < 8; ++i) {
        int c = tid + i * 256;
        int nr = c >> 4, kq = c & 15;
        *(u16x8*)&sB[nr * LDK + kq * 8] = Wv[c];
    }
#pragma unroll
    for (int i = 0; i < 8; ++i) {
        int c = tid + i * 256;
        int r = c >> 5, cq = c & 31;
        float4 v = make_float4(0.f, 0.f, 0.f, 0.f);
        if (r0 + r < n) v = ((const float4*)x)[(size_t)(r0 + r) * 32 + cq];
        f16x4 h;
        h[0] = (_Float16)v.x; h[1] = (_Float16)v.y;
        h[2] = (_Float16)v.z; h[3] = (_Float16)v.w;
        *(f16x4*)&sA[r * LDK + cq * 4] = h;
    }
    __syncthreads();

    const int lane = tid & 63, w = tid >> 6;
    const int mh = (w >> 1) * 32;
    const int nh = (w & 1) * 64;
    const int fr = lane & 15, fg = lane >> 4;

    f32x4 acc[2][4];
#pragma unroll
    for (int a = 0; a < 2; ++a)
#pragma unroll
        for (int bq = 0; bq < 4; ++bq) acc[a][bq] = (f32x4){0.f, 0.f, 0.f, 0.f};

#pragma unroll
    for (int ks = 0; ks < 8; ++ks) {
        const int kk = ks * 16 + fg * 4;
        f16x4 a0 = *(const f16x4*)&sA[(mh + fr) * LDK + kk];
        f16x4 a1 = *(const f16x4*)&sA[(mh + 16 + fr) * LDK + kk];
        f16x4 b0 = *(const f16x4*)&sB[(nh + fr) * LDK + kk];
        f16x4 b1 = *(const f16x4*)&sB[(nh + 16 + fr) * LDK + kk];
        f16x4 b2 = *(const f16x4*)&sB[(nh + 32 + fr) * LDK + kk];
        f16x4 b3 = *(const f16x4*)&sB[(nh + 48 + fr) * LDK + kk];
        acc[0][0] = __builtin_amdgcn_mfma_f32_16x16x16f16(a0, b0, acc[0][0], 0, 0, 0);
        acc[0][1] = __builtin_amdgcn_mfma_f32_16x16x16f16(a0, b1, acc[0][1], 0, 0, 0);
        acc[0][2] = __builtin_amdgcn_mfma_f32_16x16x16f16(a0, b2, acc[0][2], 0, 0, 0);
        acc[0][3] = __builtin_amdgcn_mfma_f32_16x16x16f16(a0, b3, acc[0][3], 0, 0, 0);
        acc[1][0] = __builtin_amdgcn_mfma_f32_16x16x16f16(a1, b0, acc[1][0], 0, 0, 0);
        acc[1][1] = __builtin_amdgcn_mfma_f32_16x16x16f16(a1, b1, acc[1][1], 0, 0, 0);
        acc[1][2] = __builtin_amdgcn_mfma_f32_16x16x16f16(a1, b2, acc[1][2], 0, 0, 0);
        acc[1][3] = __builtin_amdgcn_mfma_f32_16x16x16f16(a1, b3, acc[1][3], 0, 0, 0);
    }

#pragma unroll
    for (int mt = 0; mt < 2; ++mt) {
        int rbase = r0 + mh + mt * 16 + fg * 4;
        float dv[4];
#pragma unroll
        for (int rg = 0; rg < 4; ++rg)
            dv[rg] = (rbase + rg < n) ? dinv[rbase + rg] : 0.f;
#pragma unroll
        for (int nt = 0; nt < 4; ++nt) {
            int col = nh + nt * 16 + fr;
#pragma unroll
            for (int rg = 0; rg < 4; ++rg) {
                if (rbase + rg < n)
                    hs_b[(size_t)(rbase + rg) * CH + col] = f2b(acc[mt][nt][rg] * dv[rg]);
            }
        }
    }
}

// ---------------- fused sort+gather per bucket --------------------------------
// Stage bucket pairs in LDS, counting-sort by node, then 16-lane groups
// register-accumulate each node's in-edges; epilogue dinv*acc + bias, relu.

__global__ __launch_bounds__(256) void k_gagg(const u16x8* __restrict__ h8,
                                              const unsigned int* __restrict__ pairs,
                                              const int* __restrict__ gcur,
                                              const unsigned int* __restrict__ spill,
                                              const float* __restrict__ dinv,
                                              const float* __restrict__ bias,
                                              float* __restrict__ out, int n, int nb) {
    __shared__ unsigned int   sPairs[CAP];
    __shared__ unsigned short sSort[CAP];
    __shared__ int scnt[BNODES], sexcl[BNODES], scur[BNODES];
    __shared__ float sdinv[BNODES];

    const int t = threadIdx.x, b = blockIdx.x;
    const int n0 = b * BNODES;

    if (t < BNODES) {
        scnt[t] = 0;
        int node = n0 + t;
        sdinv[t] = (node < n) ? dinv[node] : 0.f;
    }
    __syncthreads();

    const int cntb = min(gcur[b], CAP);
    const unsigned int* pp = pairs + (size_t)b * CAP;
    for (int j = t; j < cntb; j += 256) {
        unsigned p = pp[j];
        sPairs[j] = p;
        atomicAdd(&scnt[p & (BNODES - 1)], 1);
    }
    __syncthreads();

    if (t < 64) {          // BNODES == 64: one wave scans the counts
        int c = scnt[t];
        int s = c;
#pragma unroll
        for (int off = 1; off < 64; off <<= 1) {
            int tv = __shfl_up(s, off, 64);
            if (t >= off) s += tv;
        }
        sexcl[t] = s - c;
        scur[t]  = s - c;
    }
    __syncthreads();

    for (int j = t; j < cntb; j += 256) {
        unsigned p = sPairs[j];
        int pos = atomicAdd(&scur[p & (BNODES - 1)], 1);
        sSort[pos] = (unsigned short)(p >> BSH);
    }
    __syncthreads();

    const int g = t >> 4, lane = t & 15;        // 16 groups of 16 lanes
    const int ns = gcur[nb];
#pragma unroll
    for (int k = 0; k < BNODES / 16; ++k) {     // 4 nodes per group
        const int nl = g * (BNODES / 16) + k;
        const int node = n0 + nl;
        if (node >= n) break;

        float acc[8];
        {
            u16x8 v = h8[(size_t)node * 16 + lane];   // self term
#pragma unroll
            for (int i = 0; i < 8; ++i) acc[i] = b2f(v[i]);
        }

        int j = sexcl[nl];
        const int end = j + scnt[nl];
        for (; j + 4 <= end; j += 4) {
            int s0 = sSort[j + 0], s1 = sSort[j + 1];
            int s2 = sSort[j + 2], s3 = sSort[j + 3];
            u16x8 v0 = h8[(size_t)s0 * 16 + lane];
            u16x8 v1 = h8[(size_t)s1 * 16 + lane];
            u16x8 v2 = h8[(size_t)s2 * 16 + lane];
            u16x8 v3 = h8[(size_t)s3 * 16 + lane];
#pragma unroll
            for (int i = 0; i < 8; ++i)
                acc[i] += (b2f(v0[i]) + b2f(v1[i])) + (b2f(v2[i]) + b2f(v3[i]));
        }
        for (; j < end; ++j) {
            u16x8 v = h8[(size_t)sSort[j] * 16 + lane];
#pragma unroll
            for (int i = 0; i < 8; ++i) acc[i] += b2f(v[i]);
        }

        if (ns > 0) {      // cold path: spilled edges for this node
            for (int q = 0; q < ns; ++q) {
                unsigned u = spill[q];
                if ((int)(u & 0xffffu) == node) {
                    u16x8 v = h8[(size_t)(u >> 16) * 16 + lane];
#pragma unroll
                    for (int i = 0; i < 8; ++i) acc[i] += b2f(v[i]);
                }
            }
        }

        const float di = sdinv[nl];
        const float* bp = bias + lane * 8;
        float4 o0, o1;
        o0.x = fmaxf(fmaf(acc[0], di, bp[0]), 0.f);
        o0.y = fmaxf(fmaf(acc[1], di, bp[1]), 0.f);
        o0.z = fmaxf(fmaf(acc[2], di, bp[2]), 0.f);
        o0.w = fmaxf(fmaf(acc[3], di, bp[3]), 0.f);
        o1.x = fmaxf(fmaf(acc[4], di, bp[4]), 0.f);
        o1.y = fmaxf(fmaf(acc[5], di, bp[5]), 0.f);
        o1.z = fmaxf(fmaf(acc[6], di, bp[6]), 0.f);
        o1.w = fmaxf(fmaf(acc[7], di, bp[7]), 0.f);
        float4* op = (float4*)(out + (size_t)node * CH + lane * 8);
        op[0] = o0;
        op[1] = o1;
    }
}

// ---------------- launch ----------------

extern "C" void kernel_launch(void* const* d_in, const int* in_sizes, int n_in,
                              void* d_out, int out_size, void* d_ws, size_t ws_size,
                              hipStream_t stream) {
    const float* x  = (const float*)d_in[0];
    const int*   ei = (const int*)d_in[1];
    const float* W  = (const float*)d_in[2];
    const float* b  = (const float*)d_in[3];
    float* out = (float*)d_out;

    const int N = in_sizes[0] / CH;     // 50000 (node ids < 65536 -> 16-bit packing valid)
    const int E = in_sizes[1] / 2;      // 800000

    const int NB = (N + BNODES - 1) / BNODES;   // 782 buckets

    // workspace layout
    size_t o_gcur  = 0;
    size_t o_dinv  = o_gcur  + align256(((size_t)NB + 1) * 4);
    size_t o_WT    = o_dinv  + align256((size_t)N * 4);
    size_t o_hs    = o_WT    + align256((size_t)CH * CH * 2);
    size_t o_pairs = o_hs    + align256((size_t)N * CH * 2);
    size_t o_spill = o_pairs + align256((size_t)NB * CAP * 4);

    int*            gcur  = (int*)((char*)d_ws + o_gcur);
    float*          dinv  = (float*)((char*)d_ws + o_dinv);
    unsigned short* WT    = (unsigned short*)((char*)d_ws + o_WT);
    unsigned short* hs_b  = (unsigned short*)((char*)d_ws + o_hs);
    unsigned int*   pairs = (unsigned int*)((char*)d_ws + o_pairs);
    unsigned int*   spill = (unsigned int*)((char*)d_ws + o_spill);

    const int gCH = (E + 4095) / 4096;          // 4096-edge chunks (196)

    hipMemsetAsync(gcur, 0, ((size_t)NB + 1) * 4, stream);
    k_bin<<<gCH, 256, 0, stream>>>(ei, gcur, pairs, spill, E, NB, W, WT);
    k_cnt<<<NB, 256, 0, stream>>>(pairs, gcur, spill, dinv, N, NB);
    k_gemm<<<(N + GM - 1) / GM, 256, 0, stream>>>(x, WT, dinv, hs_b, N);
    k_gagg<<<NB, 256, 0, stream>>>((const u16x8*)hs_b, pairs, gcur, spill, dinv, b, out, N, NB);
}

// Round 7
// 75.368 us; speedup vs baseline: 19.2929x; 1.1166x over previous
//
#include <hip/hip_runtime.h>

#define CH 128          // IN_CH == OUT_CH == 128
#define GM 64           // rows per GEMM block == BNODES (gemm block b == bucket b)
#define LDK 136         // padded K stride in LDS
#define BSH 6           // log2(nodes per bucket)
#define BNODES 64       // nodes per bucket
#define CAP 3072        // per-bucket pair capacity (lambda=1024; spill handles excess)
#define MAXB 1024       // LDS cap for bucket arrays (NB=782 for N=50000)

typedef _Float16 f16x4 __attribute__((ext_vector_type(4)));
typedef float    f32x4 __attribute__((ext_vector_type(4)));
typedef unsigned short u16x8 __attribute__((ext_vector_type(8)));

static __host__ __device__ inline size_t align256(size_t x) { return (x + 255) & ~(size_t)255; }

__device__ inline unsigned short f2b(float f) {   // fp32 -> bf16 RNE
    unsigned int u = __float_as_uint(f);
    return (unsigned short)((u + 0x7fffu + ((u >> 16) & 1u)) >> 16);
}
__device__ inline float b2f(unsigned short h) {
    return __uint_as_float(((unsigned int)h) << 16);
}

// ---------------- bin edges into fixed-capacity buckets + W f16-transpose --------
// pairs[b*CAP + slot] = (src<<6)|(dst&63).  Overflow -> spill list (normally empty).

__global__ __launch_bounds__(256) void k_bin(const int* __restrict__ ei,
                                             int* __restrict__ gcur,      // [nb+1]; [nb]=spill cnt
                                             unsigned int* __restrict__ pairs,
                                             unsigned int* __restrict__ spill,
                                             int e, int nb,
                                             const float* __restrict__ W,
                                             unsigned short* __restrict__ WT) {
    __shared__ int lcnt[MAXB], lbase[MAXB], lpos[MAXB];
    const int t = threadIdx.x;

    // fused W prep: fp32 [k][n] -> f16 bits transposed [n][k]; first 8 blocks
    if (blockIdx.x < 8) {
        int wb = blockIdx.x * 2048;
#pragma unroll
        for (int i = 0; i < 8; ++i) {
            int idx = wb + t + i * 256;
            int k = idx >> 7, nn = idx & 127;
            _Float16 h = (_Float16)W[idx];
            WT[nn * CH + k] = *(unsigned short*)&h;
        }
    }

    for (int i = t; i < nb; i += 256) { lcnt[i] = 0; lpos[i] = 0; }
    __syncthreads();

    // stage 16 edges/thread via int4 (src and dst planes both 16B-aligned per block)
    const int base = blockIdx.x * 4096;
    const int e4 = e >> 2;                       // e % 4 == 0 for this problem
    int4 s4[4], d4[4];
#pragma unroll
    for (int r = 0; r < 4; ++r) {
        int q = (base >> 2) + t + r * 256;
        if (q < e4) {
            s4[r] = ((const int4*)ei)[q];
            d4[r] = ((const int4*)(ei + e))[q];
        } else {
            s4[r] = make_int4(-1, -1, -1, -1);
            d4[r] = make_int4(0, 0, 0, 0);
        }
    }
    const int* ss = (const int*)s4;
    const int* dd = (const int*)d4;
#pragma unroll
    for (int i = 0; i < 16; ++i)
        if (ss[i] >= 0) atomicAdd(&lcnt[dd[i] >> BSH], 1);
    __syncthreads();
    for (int i = t; i < nb; i += 256)
        if (lcnt[i]) lbase[i] = atomicAdd(&gcur[i], lcnt[i]);
    __syncthreads();
#pragma unroll
    for (int i = 0; i < 16; ++i) {
        if (ss[i] >= 0) {
            int b = dd[i] >> BSH;
            int p = lbase[b] + atomicAdd(&lpos[b], 1);
            if (p < CAP) {
                pairs[(size_t)b * CAP + p] = ((unsigned)ss[i] << BSH) | (unsigned)(dd[i] & (BNODES - 1));
            } else {
                int sp = atomicAdd(&gcur[nb], 1);
                spill[sp] = ((unsigned)ss[i] << 16) | (unsigned)dd[i];
            }
        }
    }
}

// ---------------- GEMM + fused per-bucket degree/dinv ---------------------------
// Block b == bucket b (GM == BNODES). Histogram of pairs -> dinv hidden under MFMA.

__global__ __launch_bounds__(256) void k_gemm(const float* __restrict__ x,
                                              const unsigned short* __restrict__ WT,
                                              const unsigned int* __restrict__ pairs,
                                              const int* __restrict__ gcur,
                                              const unsigned int* __restrict__ spill,
                                              float* __restrict__ dinv,
                                              unsigned short* __restrict__ hs_b,
                                              int n, int nb) {
    __shared__ unsigned short sA[GM * LDK];
    __shared__ unsigned short sB[CH * LDK];
    __shared__ int   scnt[GM];
    __shared__ float sdv[GM];

    const int tid = threadIdx.x;
    const int b   = blockIdx.x;
    const int r0  = b * GM;

    if (tid < GM) scnt[tid] = 0;

    const u16x8* Wv = (const u16x8*)WT;
#pragma unroll
    for (int i = 0; i < 8; ++i) {
        int c = tid + i * 256;
        int nr = c >> 4, kq = c & 15;
        *(u16x8*)&sB[nr * LDK + kq * 8] = Wv[c];
    }
#pragma unroll
    for (int i = 0; i < 8; ++i) {
        int c = tid + i * 256;
        int r = c >> 5, cq = c & 31;
        float4 v = make_float4(0.f, 0.f, 0.f, 0.f);
        if (r0 + r < n) v = ((const float4*)x)[(size_t)(r0 + r) * 32 + cq];
        f16x4 h;
        h[0] = (_Float16)v.x; h[1] = (_Float16)v.y;
        h[2] = (_Float16)v.z; h[3] = (_Float16)v.w;
        *(f16x4*)&sA[r * LDK + cq * 4] = h;
    }
    __syncthreads();

    // fused degree histogram (overlaps with MFMA issue below)
    {
        const int cntb = min(gcur[b], CAP);
        const unsigned int* pp = pairs + (size_t)b * CAP;
        for (int j = tid; j < cntb; j += 256)
            atomicAdd(&scnt[pp[j] & (BNODES - 1)], 1);
        const int ns = gcur[nb];
        if (ns > 0) {
            for (int j = tid; j < ns; j += 256) {
                unsigned u = spill[j];
                unsigned du = u & 0xffffu;
                if ((int)(du >> BSH) == b) atomicAdd(&scnt[du & (BNODES - 1)], 1);
            }
        }
    }

    const int lane = tid & 63, w = tid >> 6;
    const int mh = (w >> 1) * 32;
    const int nh = (w & 1) * 64;
    const int fr = lane & 15, fg = lane >> 4;

    f32x4 acc[2][4];
#pragma unroll
    for (int a = 0; a < 2; ++a)
#pragma unroll
        for (int bq = 0; bq < 4; ++bq) acc[a][bq] = (f32x4){0.f, 0.f, 0.f, 0.f};

#pragma unroll
    for (int ks = 0; ks < 8; ++ks) {
        const int kk = ks * 16 + fg * 4;
        f16x4 a0 = *(const f16x4*)&sA[(mh + fr) * LDK + kk];
        f16x4 a1 = *(const f16x4*)&sA[(mh + 16 + fr) * LDK + kk];
        f16x4 b0 = *(const f16x4*)&sB[(nh + fr) * LDK + kk];
        f16x4 b1 = *(const f16x4*)&sB[(nh + 16 + fr) * LDK + kk];
        f16x4 b2 = *(const f16x4*)&sB[(nh + 32 + fr) * LDK + kk];
        f16x4 b3 = *(const f16x4*)&sB[(nh + 48 + fr) * LDK + kk];
        acc[0][0] = __builtin_amdgcn_mfma_f32_16x16x16f16(a0, b0, acc[0][0], 0, 0, 0);
        acc[0][1] = __builtin_amdgcn_mfma_f32_16x16x16f16(a0, b1, acc[0][1], 0, 0, 0);
        acc[0][2] = __builtin_amdgcn_mfma_f32_16x16x16f16(a0, b2, acc[0][2], 0, 0, 0);
        acc[0][3] = __builtin_amdgcn_mfma_f32_16x16x16f16(a0, b3, acc[0][3], 0, 0, 0);
        acc[1][0] = __builtin_amdgcn_mfma_f32_16x16x16f16(a1, b0, acc[1][0], 0, 0, 0);
        acc[1][1] = __builtin_amdgcn_mfma_f32_16x16x16f16(a1, b1, acc[1][1], 0, 0, 0);
        acc[1][2] = __builtin_amdgcn_mfma_f32_16x16x16f16(a1, b2, acc[1][2], 0, 0, 0);
        acc[1][3] = __builtin_amdgcn_mfma_f32_16x16x16f16(a1, b3, acc[1][3], 0, 0, 0);
    }
    __syncthreads();                 // histogram atomics complete

    if (tid < GM) {
        float dv = rsqrtf((float)scnt[tid] + 1.0f);
        sdv[tid] = dv;
        int node = r0 + tid;
        if (node < n) dinv[node] = dv;
    }
    __syncthreads();                 // sdv visible to all

#pragma unroll
    for (int mt = 0; mt < 2; ++mt) {
        int lbase_r = mh + mt * 16 + fg * 4;
        int rbase = r0 + lbase_r;
#pragma unroll
        for (int nt = 0; nt < 4; ++nt) {
            int col = nh + nt * 16 + fr;
#pragma unroll
            for (int rg = 0; rg < 4; ++rg) {
                if (rbase + rg < n)
                    hs_b[(size_t)(rbase + rg) * CH + col] = f2b(acc[mt][nt][rg] * sdv[lbase_r + rg]);
            }
        }
    }
}

// ---------------- fused sort+gather per bucket --------------------------------

__global__ __launch_bounds__(256) void k_gagg(const u16x8* __restrict__ h8,
                                              const unsigned int* __restrict__ pairs,
                                              const int* __restrict__ gcur,
                                              const unsigned int* __restrict__ spill,
                                              const float* __restrict__ dinv,
                                              const float* __restrict__ bias,
                                              float* __restrict__ out, int n, int nb) {
    __shared__ unsigned int   sPairs[CAP];
    __shared__ unsigned short sSort[CAP];
    __shared__ int scnt[BNODES], sexcl[BNODES], scur[BNODES];
    __shared__ float sdinv[BNODES];

    const int t = threadIdx.x, b = blockIdx.x;
    const int n0 = b * BNODES;

    if (t < BNODES) {
        scnt[t] = 0;
        int node = n0 + t;
        sdinv[t] = (node < n) ? dinv[node] : 0.f;
    }
    __syncthreads();

    const int cntb = min(gcur[b], CAP);
    const unsigned int* pp = pairs + (size_t)b * CAP;
    for (int j = t; j < cntb; j += 256) {
        unsigned p = pp[j];
        sPairs[j] = p;
        atomicAdd(&scnt[p & (BNODES - 1)], 1);
    }
    __syncthreads();

    if (t < 64) {          // BNODES == 64: one wave scans the counts
        int c = scnt[t];
        int s = c;
#pragma unroll
        for (int off = 1; off < 64; off <<= 1) {
            int tv = __shfl_up(s, off, 64);
            if (t >= off) s += tv;
        }
        sexcl[t] = s - c;
        scur[t]  = s - c;
    }
    __syncthreads();

    for (int j = t; j < cntb; j += 256) {
        unsigned p = sPairs[j];
        int pos = atomicAdd(&scur[p & (BNODES - 1)], 1);
        sSort[pos] = (unsigned short)(p >> BSH);
    }
    __syncthreads();

    const int g = t >> 4, lane = t & 15;        // 16 groups of 16 lanes
    const int ns = gcur[nb];
#pragma unroll
    for (int k = 0; k < BNODES / 16; ++k) {     // 4 nodes per group
        const int nl = g * (BNODES / 16) + k;
        const int node = n0 + nl;
        if (node >= n) break;

        float acc[8];
        {
            u16x8 v = h8[(size_t)node * 16 + lane];   // self term
#pragma unroll
            for (int i = 0; i < 8; ++i) acc[i] = b2f(v[i]);
        }

        int j = sexcl[nl];
        const int end = j + scnt[nl];
        for (; j + 4 <= end; j += 4) {
            int s0 = sSort[j + 0], s1 = sSort[j + 1];
            int s2 = sSort[j + 2], s3 = sSort[j + 3];
            u16x8 v0 = h8[(size_t)s0 * 16 + lane];
            u16x8 v1 = h8[(size_t)s1 * 16 + lane];
            u16x8 v2 = h8[(size_t)s2 * 16 + lane];
            u16x8 v3 = h8[(size_t)s3 * 16 + lane];
#pragma unroll
            for (int i = 0; i < 8; ++i)
                acc[i] += (b2f(v0[i]) + b2f(v1[i])) + (b2f(v2[i]) + b2f(v3[i]));
        }
        for (; j < end; ++j) {
            u16x8 v = h8[(size_t)sSort[j] * 16 + lane];
#pragma unroll
            for (int i = 0; i < 8; ++i) acc[i] += b2f(v[i]);
        }

        if (ns > 0) {      // cold path: spilled edges for this node
            for (int q = 0; q < ns; ++q) {
                unsigned u = spill[q];
                if ((int)(u & 0xffffu) == node) {
                    u16x8 v = h8[(size_t)(u >> 16) * 16 + lane];
#pragma unroll
                    for (int i = 0; i < 8; ++i) acc[i] += b2f(v[i]);
                }
            }
        }

        const float di = sdinv[nl];
        const float* bp = bias + lane * 8;
        float4 o0, o1;
        o0.x = fmaxf(fmaf(acc[0], di, bp[0]), 0.f);
        o0.y = fmaxf(fmaf(acc[1], di, bp[1]), 0.f);
        o0.z = fmaxf(fmaf(acc[2], di, bp[2]), 0.f);
        o0.w = fmaxf(fmaf(acc[3], di, bp[3]), 0.f);
        o1.x = fmaxf(fmaf(acc[4], di, bp[4]), 0.f);
        o1.y = fmaxf(fmaf(acc[5], di, bp[5]), 0.f);
        o1.z = fmaxf(fmaf(acc[6], di, bp[6]), 0.f);
        o1.w = fmaxf(fmaf(acc[7], di, bp[7]), 0.f);
        float4* op = (float4*)(out + (size_t)node * CH + lane * 8);
        op[0] = o0;
        op[1] = o1;
    }
}

// ---------------- launch ----------------

extern "C" void kernel_launch(void* const* d_in, const int* in_sizes, int n_in,
                              void* d_out, int out_size, void* d_ws, size_t ws_size,
                              hipStream_t stream) {
    const float* x  = (const float*)d_in[0];
    const int*   ei = (const int*)d_in[1];
    const float* W  = (const float*)d_in[2];
    const float* b  = (const float*)d_in[3];
    float* out = (float*)d_out;

    const int N = in_sizes[0] / CH;     // 50000 (node ids < 65536 -> 16-bit packing valid)
    const int E = in_sizes[1] / 2;      // 800000

    const int NB = (N + BNODES - 1) / BNODES;   // 782 buckets == gemm blocks

    // workspace layout
    size_t o_gcur  = 0;
    size_t o_dinv  = o_gcur  + align256(((size_t)NB + 1) * 4);
    size_t o_WT    = o_dinv  + align256((size_t)N * 4);
    size_t o_hs    = o_WT    + align256((size_t)CH * CH * 2);
    size_t o_pairs = o_hs    + align256((size_t)N * CH * 2);
    size_t o_spill = o_pairs + align256((size_t)NB * CAP * 4);

    int*            gcur  = (int*)((char*)d_ws + o_gcur);
    float*          dinv  = (float*)((char*)d_ws + o_dinv);
    unsigned short* WT    = (unsigned short*)((char*)d_ws + o_WT);
    unsigned short* hs_b  = (unsigned short*)((char*)d_ws + o_hs);
    unsigned int*   pairs = (unsigned int*)((char*)d_ws + o_pairs);
    unsigned int*   spill = (unsigned int*)((char*)d_ws + o_spill);

    const int gCH = (E + 4095) / 4096;          // 4096-edge chunks (196)

    hipMemsetAsync(gcur, 0, ((size_t)NB + 1) * 4, stream);
    k_bin<<<gCH, 256, 0, stream>>>(ei, gcur, pairs, spill, E, NB, W, WT);
    k_gemm<<<NB, 256, 0, stream>>>(x, WT, pairs, gcur, spill, dinv, hs_b, N, NB);
    k_gagg<<<NB, 256, 0, stream>>>((const u16x8*)hs_b, pairs, gcur, spill, dinv, b, out, N, NB);
}